// Round 1
// baseline (238.710 us; speedup 1.0000x reference)
//
#include <hip/hip_runtime.h>
#include <hip/hip_bf16.h>

#define Bn 4096
#define NF 20
#define NEMB 16
#define HIDN 512
#define KE 16
#define GIN 320   // NF*NEMB

// ---------------- init: zero y[Bn+1] and per-expert counters ----------------
__global__ __launch_bounds__(256) void init_kernel(float* __restrict__ out,
                                                   int* __restrict__ cnt) {
  int t = blockIdx.x * 256 + threadIdx.x;
  if (t < Bn + 1) out[t] = 0.f;
  if (t < KE) cnt[t] = 0;
}

// ---------------- gate: h=relu(sql_emb@gw1+gb1); logits; softmax; top-2 ------
__global__ __launch_bounds__(256) void gate_kernel(
    const int* __restrict__ sql, const float* __restrict__ semb_w,
    const float* __restrict__ gw1, const float* __restrict__ gb1,
    const float* __restrict__ gw2, const float* __restrict__ gb2,
    int* __restrict__ cnt, int* __restrict__ list, float* __restrict__ wlist) {
  __shared__ __align__(16) float s_emb[16][GIN];
  __shared__ __align__(16) float s_h[16][HIDN];
  __shared__ float s_l[16][16];
  const int tid = threadIdx.x;
  const int row0 = blockIdx.x * 16;

  // gather sql embeddings: 16 rows x 20 fields x 16 floats
  for (int p = tid; p < 16 * NF; p += 256) {
    int r = p / NF, f = p % NF;
    int idx = sql[(row0 + r) * NF + f];
    const float4* src = (const float4*)(semb_w + (size_t)idx * NEMB);
    float4* dst = (float4*)&s_emb[r][f * NEMB];
    dst[0] = src[0]; dst[1] = src[1]; dst[2] = src[2]; dst[3] = src[3];
  }
  __syncthreads();

  // h = relu(s_emb @ gw1 + gb1): thread = (rg in 0..3 rows-group, jt in 0..63)
  const int jt = tid & 63;
  const int rg = tid >> 6;
  const int j0 = jt * 4;
  const int j1 = j0 + 256;
  float acc[4][8];
#pragma unroll
  for (int h = 0; h < 4; h++) {
    float b0 = gb1[j0 + h], b1v = gb1[j1 + h];
#pragma unroll
    for (int r = 0; r < 4; r++) { acc[r][h] = b0; acc[r][4 + h] = b1v; }
  }
  for (int i = 0; i < GIN; i += 4) {
    float4 wa[4], wb[4];
#pragma unroll
    for (int ii = 0; ii < 4; ii++) {
      wa[ii] = *(const float4*)(gw1 + (size_t)(i + ii) * HIDN + j0);
      wb[ii] = *(const float4*)(gw1 + (size_t)(i + ii) * HIDN + j1);
    }
#pragma unroll
    for (int r = 0; r < 4; r++) {
      float4 xv = *(const float4*)&s_emb[rg * 4 + r][i];
      float xs[4] = {xv.x, xv.y, xv.z, xv.w};
#pragma unroll
      for (int ii = 0; ii < 4; ii++) {
        acc[r][0] += xs[ii] * wa[ii].x;
        acc[r][1] += xs[ii] * wa[ii].y;
        acc[r][2] += xs[ii] * wa[ii].z;
        acc[r][3] += xs[ii] * wa[ii].w;
        acc[r][4] += xs[ii] * wb[ii].x;
        acc[r][5] += xs[ii] * wb[ii].y;
        acc[r][6] += xs[ii] * wb[ii].z;
        acc[r][7] += xs[ii] * wb[ii].w;
      }
    }
  }
#pragma unroll
  for (int r = 0; r < 4; r++) {
    float4 v0, v1;
    v0.x = fmaxf(acc[r][0], 0.f); v0.y = fmaxf(acc[r][1], 0.f);
    v0.z = fmaxf(acc[r][2], 0.f); v0.w = fmaxf(acc[r][3], 0.f);
    v1.x = fmaxf(acc[r][4], 0.f); v1.y = fmaxf(acc[r][5], 0.f);
    v1.z = fmaxf(acc[r][6], 0.f); v1.w = fmaxf(acc[r][7], 0.f);
    *(float4*)&s_h[rg * 4 + r][j0] = v0;
    *(float4*)&s_h[rg * 4 + r][j1] = v1;
  }
  __syncthreads();

  // logits: one thread per (row, expert)
  {
    int r = tid >> 4, k = tid & 15;
    float a = gb2[k];
    for (int i = 0; i < HIDN; i++) a += s_h[r][i] * gw2[i * KE + k];
    s_l[r][k] = a;
  }
  __syncthreads();

  // softmax + top-2 + bucket per expert (one thread per row)
  if (tid < 16) {
    int r = tid;
    int b = row0 + r;
    float m = s_l[r][0];
#pragma unroll
    for (int q = 1; q < KE; q++) m = fmaxf(m, s_l[r][q]);
    float e[KE];
#pragma unroll
    for (int q = 0; q < KE; q++) e[q] = expf(s_l[r][q] - m);
    int i1 = 0; float v1 = e[0];
#pragma unroll
    for (int q = 1; q < KE; q++) if (e[q] > v1) { v1 = e[q]; i1 = q; }
    int i2 = (i1 == 0) ? 1 : 0; float v2 = e[i2];
#pragma unroll
    for (int q = 0; q < KE; q++)
      if (q != i1 && e[q] > v2) { v2 = e[q]; i2 = q; }
    float den = v1 + v2;
    float wv1 = v1 / den, wv2 = v2 / den;
    int p1 = atomicAdd(&cnt[i1], 1);
    list[i1 * Bn + p1] = b; wlist[i1 * Bn + p1] = wv1;
    int p2 = atomicAdd(&cnt[i2], 1);
    list[i2 * Bn + p2] = b; wlist[i2 * Bn + p2] = wv2;
  }
}

// ---------------- experts: per-expert batched rows, fused 2-layer MLP -------
__global__ __launch_bounds__(256) void expert_kernel(
    const int* __restrict__ x, const float* __restrict__ demb_w,
    const float* __restrict__ ew1, const float* __restrict__ eb1,
    const float* __restrict__ ew2, const float* __restrict__ eb2,
    const int* __restrict__ cnt, const int* __restrict__ list,
    const float* __restrict__ wlist, float* __restrict__ y) {
  const int k = blockIdx.y;
  const int n = cnt[k];
  const int base = blockIdx.x * 16;
  if (base >= n) return;
  __shared__ __align__(16) float xe[16][GIN];
  __shared__ int rid[16];
  __shared__ float rw[16];
  const int tid = threadIdx.x;
  if (tid < 16) {
    if (base + tid < n) {
      rid[tid] = list[k * Bn + base + tid];
      rw[tid] = wlist[k * Bn + base + tid];
    } else {
      rid[tid] = 0; rw[tid] = 0.f;
    }
  }
  __syncthreads();
  // gather x embeddings for these rows
  for (int p = tid; p < 16 * NF; p += 256) {
    int r = p / NF, f = p % NF;
    float4* dst = (float4*)&xe[r][f * NEMB];
    if (base + r < n) {
      int bb = rid[r];
      int idx = x[bb * NF + f];
      const float4* src = (const float4*)(demb_w + (size_t)idx * NEMB);
      dst[0] = src[0]; dst[1] = src[1]; dst[2] = src[2]; dst[3] = src[3];
    } else {
      float4 z = {0.f, 0.f, 0.f, 0.f};
      dst[0] = z; dst[1] = z; dst[2] = z; dst[3] = z;
    }
  }
  __syncthreads();

  const int jt = tid & 63;
  const int rg = tid >> 6;
  const int j0 = jt * 4, j1 = j0 + 256;
  const float* __restrict__ W = ew1 + (size_t)k * GIN * HIDN;
  const float* __restrict__ b1 = eb1 + k * HIDN;
  float acc[4][8];
#pragma unroll
  for (int h = 0; h < 4; h++) {
    float bb0 = b1[j0 + h], bb1 = b1[j1 + h];
#pragma unroll
    for (int r = 0; r < 4; r++) { acc[r][h] = bb0; acc[r][4 + h] = bb1; }
  }
  for (int i = 0; i < GIN; i += 4) {
    float4 wa[4], wb[4];
#pragma unroll
    for (int ii = 0; ii < 4; ii++) {
      wa[ii] = *(const float4*)(W + (size_t)(i + ii) * HIDN + j0);
      wb[ii] = *(const float4*)(W + (size_t)(i + ii) * HIDN + j1);
    }
#pragma unroll
    for (int r = 0; r < 4; r++) {
      float4 xv = *(const float4*)&xe[rg * 4 + r][i];
      float xs[4] = {xv.x, xv.y, xv.z, xv.w};
#pragma unroll
      for (int ii = 0; ii < 4; ii++) {
        acc[r][0] += xs[ii] * wa[ii].x;
        acc[r][1] += xs[ii] * wa[ii].y;
        acc[r][2] += xs[ii] * wa[ii].z;
        acc[r][3] += xs[ii] * wa[ii].w;
        acc[r][4] += xs[ii] * wb[ii].x;
        acc[r][5] += xs[ii] * wb[ii].y;
        acc[r][6] += xs[ii] * wb[ii].z;
        acc[r][7] += xs[ii] * wb[ii].w;
      }
    }
  }
  // fused relu + second layer (OUT=1) partial dot
  const float* __restrict__ w2 = ew2 + k * HIDN;
  float w2a[4] = {w2[j0], w2[j0 + 1], w2[j0 + 2], w2[j0 + 3]};
  float w2b[4] = {w2[j1], w2[j1 + 1], w2[j1 + 2], w2[j1 + 3]};
  float part[4];
#pragma unroll
  for (int r = 0; r < 4; r++) {
    float p = 0.f;
#pragma unroll
    for (int h = 0; h < 4; h++) {
      p += fmaxf(acc[r][h], 0.f) * w2a[h];
      p += fmaxf(acc[r][4 + h], 0.f) * w2b[h];
    }
    part[r] = p;
  }
  // wave-level reduce across 64 jt lanes (all lanes in a wave share rg)
#pragma unroll
  for (int off = 32; off > 0; off >>= 1) {
#pragma unroll
    for (int r = 0; r < 4; r++) part[r] += __shfl_down(part[r], off);
  }
  if (jt == 0) {
    float e2 = eb2[k];
#pragma unroll
    for (int r = 0; r < 4; r++) {
      int rr = rg * 4 + r;
      atomicAdd(&y[rid[rr]], rw[rr] * (part[r] + e2));
    }
  }
}

// ---------------- loss: importance/load CV^2 --------------------------------
__global__ __launch_bounds__(256) void loss_kernel(const int* __restrict__ cnt,
                                                   const float* __restrict__ wlist,
                                                   float* __restrict__ out) {
  __shared__ float simp[KE][KE];
  __shared__ float fimp[KE];
  const int tid = threadIdx.x;
  const int k = tid >> 4, g = tid & 15;
  const int n = cnt[k];
  float s = 0.f;
  for (int j = g; j < n; j += 16) s += wlist[k * Bn + j];
  simp[k][g] = s;
  __syncthreads();
  if (tid < KE) {
    float t = 0.f;
    for (int q = 0; q < KE; q++) t += simp[tid][q];
    fimp[tid] = t;
  }
  __syncthreads();
  if (tid == 0) {
    double mi = 0.0, ml = 0.0;
    for (int q = 0; q < KE; q++) { mi += fimp[q]; ml += (double)cnt[q]; }
    mi /= KE; ml /= KE;
    double vi = 0.0, vl = 0.0;
    for (int q = 0; q < KE; q++) {
      double di = fimp[q] - mi; vi += di * di;
      double dl = (double)cnt[q] - ml; vl += dl * dl;
    }
    vi /= KE; vl /= KE;
    double loss = vi / (mi * mi + 1e-10) + vl / (ml * ml + 1e-10);
    out[Bn] = (float)loss;
  }
}

extern "C" void kernel_launch(void* const* d_in, const int* in_sizes, int n_in,
                              void* d_out, int out_size, void* d_ws, size_t ws_size,
                              hipStream_t stream) {
  const int* x      = (const int*)d_in[0];
  const int* sql    = (const int*)d_in[1];
  const float* semb = (const float*)d_in[2];
  const float* demb = (const float*)d_in[3];
  const float* gw1  = (const float*)d_in[4];
  const float* gb1  = (const float*)d_in[5];
  const float* gw2  = (const float*)d_in[6];
  const float* gb2  = (const float*)d_in[7];
  const float* ew1  = (const float*)d_in[8];
  const float* eb1  = (const float*)d_in[9];
  const float* ew2  = (const float*)d_in[10];
  const float* eb2  = (const float*)d_in[11];
  float* y = (float*)d_out;

  char* ws = (char*)d_ws;
  int* cnt    = (int*)ws;                              // 16 ints
  int* list   = (int*)(ws + 1024);                     // KE*Bn ints (256 KB)
  float* wlist = (float*)(ws + 1024 + sizeof(int) * KE * Bn);  // KE*Bn floats

  init_kernel<<<(Bn + 1 + 255) / 256, 256, 0, stream>>>(y, cnt);
  gate_kernel<<<Bn / 16, 256, 0, stream>>>(sql, semb, gw1, gb1, gw2, gb2,
                                           cnt, list, wlist);
  expert_kernel<<<dim3(Bn / 16, KE), 256, 0, stream>>>(x, demb, ew1, eb1, ew2,
                                                       eb2, cnt, list, wlist, y);
  loss_kernel<<<1, 256, 0, stream>>>(cnt, wlist, y);
}

// Round 2
// 188.194 us; speedup vs baseline: 1.2684x; 1.2684x over previous
//
#include <hip/hip_runtime.h>
#include <hip/hip_bf16.h>

#define Bn 4096
#define NF 20
#define NEMB 16
#define HIDN 512
#define KE 16
#define GIN 320
#define BI 4            // K-rows per LDS stage
#define NS (GIN / BI)   // 80 stages

__device__ __forceinline__ void gload_lds16(const float* g, float* l) {
  // each lane supplies its own global address; LDS dest = uniform base + lane*16
  __builtin_amdgcn_global_load_lds(
      (const __attribute__((address_space(1))) unsigned int*)g,
      (__attribute__((address_space(3))) unsigned int*)l, 16, 0, 0);
}

// ---------------- init ------------------------------------------------------
__global__ __launch_bounds__(256) void init_kernel(float* __restrict__ out,
                                                   int* __restrict__ cnt) {
  int t = blockIdx.x * 256 + threadIdx.x;
  if (t < Bn + 1) out[t] = 0.f;
  if (t < KE) cnt[t] = 0;
}

// ---------------- gate ------------------------------------------------------
__global__ __launch_bounds__(256) void gate_kernel(
    const int* __restrict__ sql, const float* __restrict__ semb_w,
    const float* __restrict__ gw1, const float* __restrict__ gb1,
    const float* __restrict__ gw2, const float* __restrict__ gb2,
    int* __restrict__ cnt, int* __restrict__ list, float* __restrict__ wlist) {
  __shared__ __align__(16) float xe[16][GIN];          // 20 KB
  __shared__ __align__(16) float wbuf[2][BI][HIDN];    // 16 KB
  __shared__ float s_l[16][KE];
  const int tid = threadIdx.x;
  const int lane = tid & 63;
  const int wv = tid >> 6;
  const int row0 = blockIdx.x * 16;

  // gather sql embeddings
  for (int p = tid; p < 16 * NF; p += 256) {
    int r = p / NF, f = p % NF;
    int idx = sql[(row0 + r) * NF + f];
    const float4* src = (const float4*)(semb_w + (size_t)idx * NEMB);
    float4* dst = (float4*)&xe[r][f * NEMB];
    dst[0] = src[0]; dst[1] = src[1]; dst[2] = src[2]; dst[3] = src[3];
  }
  // prologue: stage K-rows 0..3 (wave wv -> row wv, 2x 1KB chunks)
  {
    const float* g = gw1 + (size_t)wv * HIDN + lane * 4;
    gload_lds16(g, &wbuf[0][wv][0]);
    gload_lds16(g + 256, &wbuf[0][wv][256]);
  }

  const int j0 = lane * 4, j1 = j0 + 256;
  float acc[4][8];
#pragma unroll
  for (int h = 0; h < 4; h++) {
    float b0 = gb1[j0 + h], b1 = gb1[j1 + h];
#pragma unroll
    for (int r = 0; r < 4; r++) { acc[r][h] = b0; acc[r][4 + h] = b1; }
  }

  for (int s = 0; s < NS; s++) {
    __syncthreads();  // wbuf[s&1] ready (vmcnt drained before barrier)
    if (s + 1 < NS) {
      const float* g = gw1 + (size_t)((s + 1) * BI + wv) * HIDN + lane * 4;
      float* l = &wbuf[(s + 1) & 1][wv][0];
      gload_lds16(g, l);
      gload_lds16(g + 256, l + 256);
    }
    const float(*wb_)[HIDN] = wbuf[s & 1];
    const int i0 = s * BI;
    float4 xv[4];
#pragma unroll
    for (int r = 0; r < 4; r++) xv[r] = *(const float4*)&xe[wv * 4 + r][i0];
#pragma unroll
    for (int ii = 0; ii < BI; ii++) {
      float4 wa = *(const float4*)&wb_[ii][j0];
      float4 wbv = *(const float4*)&wb_[ii][j1];
#pragma unroll
      for (int r = 0; r < 4; r++) {
        const float* xp = (const float*)&xv[r];
        float xs = xp[ii];
        acc[r][0] = fmaf(xs, wa.x, acc[r][0]);
        acc[r][1] = fmaf(xs, wa.y, acc[r][1]);
        acc[r][2] = fmaf(xs, wa.z, acc[r][2]);
        acc[r][3] = fmaf(xs, wa.w, acc[r][3]);
        acc[r][4] = fmaf(xs, wbv.x, acc[r][4]);
        acc[r][5] = fmaf(xs, wbv.y, acc[r][5]);
        acc[r][6] = fmaf(xs, wbv.z, acc[r][6]);
        acc[r][7] = fmaf(xs, wbv.w, acc[r][7]);
      }
    }
  }

  // logits: in-register contraction of my 8 h-columns with gw2, then
  // wave butterfly reduce (no h round-trip through LDS)
  float part[4][KE];
#pragma unroll
  for (int r = 0; r < 4; r++)
#pragma unroll
    for (int q = 0; q < KE; q++) part[r][q] = 0.f;
#pragma unroll
  for (int cc = 0; cc < 4; cc++) {
    const float* g0 = gw2 + (size_t)(j0 + cc) * KE;
    const float* g1 = gw2 + (size_t)(j1 + cc) * KE;
    float4 ga[4], gb[4];
#pragma unroll
    for (int u = 0; u < 4; u++) {
      ga[u] = *(const float4*)(g0 + u * 4);
      gb[u] = *(const float4*)(g1 + u * 4);
    }
#pragma unroll
    for (int r = 0; r < 4; r++) {
      float h0 = fmaxf(acc[r][cc], 0.f);
      float h1 = fmaxf(acc[r][4 + cc], 0.f);
#pragma unroll
      for (int u = 0; u < 4; u++) {
        part[r][u * 4 + 0] += h0 * ga[u].x + h1 * gb[u].x;
        part[r][u * 4 + 1] += h0 * ga[u].y + h1 * gb[u].y;
        part[r][u * 4 + 2] += h0 * ga[u].z + h1 * gb[u].z;
        part[r][u * 4 + 3] += h0 * ga[u].w + h1 * gb[u].w;
      }
    }
  }
#pragma unroll
  for (int off = 1; off < 64; off <<= 1) {
#pragma unroll
    for (int r = 0; r < 4; r++)
#pragma unroll
      for (int q = 0; q < KE; q++)
        part[r][q] += __shfl_xor(part[r][q], off);
  }
  if (lane == 0) {
#pragma unroll
    for (int r = 0; r < 4; r++)
#pragma unroll
      for (int q = 0; q < KE; q++) s_l[wv * 4 + r][q] = part[r][q];
  }
  __syncthreads();

  if (tid < 16) {
    int r = tid;
    int b = row0 + r;
    float lg[KE];
#pragma unroll
    for (int q = 0; q < KE; q++) lg[q] = s_l[r][q] + gb2[q];
    float m = lg[0];
#pragma unroll
    for (int q = 1; q < KE; q++) m = fmaxf(m, lg[q]);
    float e[KE];
#pragma unroll
    for (int q = 0; q < KE; q++) e[q] = expf(lg[q] - m);
    int i1 = 0; float v1 = e[0];
#pragma unroll
    for (int q = 1; q < KE; q++) if (e[q] > v1) { v1 = e[q]; i1 = q; }
    int i2 = (i1 == 0) ? 1 : 0; float v2 = e[i2];
#pragma unroll
    for (int q = 0; q < KE; q++)
      if (q != i1 && e[q] > v2) { v2 = e[q]; i2 = q; }
    float den = v1 + v2;
    int p1 = atomicAdd(&cnt[i1], 1);
    list[i1 * Bn + p1] = b; wlist[i1 * Bn + p1] = v1 / den;
    int p2 = atomicAdd(&cnt[i2], 1);
    list[i2 * Bn + p2] = b; wlist[i2 * Bn + p2] = v2 / den;
  }
}

// ---------------- experts ---------------------------------------------------
__global__ __launch_bounds__(256) void expert_kernel(
    const int* __restrict__ x, const float* __restrict__ demb_w,
    const float* __restrict__ ew1, const float* __restrict__ eb1,
    const float* __restrict__ ew2, const float* __restrict__ eb2,
    const int* __restrict__ cnt, const int* __restrict__ list,
    const float* __restrict__ wlist, float* __restrict__ y) {
  const int k = blockIdx.y;
  const int n = cnt[k];
  const int base = blockIdx.x * 16;
  if (base >= n) return;
  __shared__ __align__(16) float xe[16][GIN];
  __shared__ __align__(16) float wbuf[2][BI][HIDN];
  __shared__ int rid[16];
  __shared__ float rw[16];
  const int tid = threadIdx.x;
  const int lane = tid & 63;
  const int wv = tid >> 6;
  if (tid < 16) {
    if (base + tid < n) {
      rid[tid] = list[k * Bn + base + tid];
      rw[tid] = wlist[k * Bn + base + tid];
    } else {
      rid[tid] = 0; rw[tid] = 0.f;   // pad rows: weight 0 nullifies output
    }
  }
  __syncthreads();

  const float* __restrict__ W = ew1 + (size_t)k * GIN * HIDN;
  for (int p = tid; p < 16 * NF; p += 256) {
    int r = p / NF, f = p % NF;
    int bb = rid[r];
    int idx = x[bb * NF + f];
    const float4* src = (const float4*)(demb_w + (size_t)idx * NEMB);
    float4* dst = (float4*)&xe[r][f * NEMB];
    dst[0] = src[0]; dst[1] = src[1]; dst[2] = src[2]; dst[3] = src[3];
  }
  {
    const float* g = W + (size_t)wv * HIDN + lane * 4;
    gload_lds16(g, &wbuf[0][wv][0]);
    gload_lds16(g + 256, &wbuf[0][wv][256]);
  }

  const int j0 = lane * 4, j1 = j0 + 256;
  const float* __restrict__ b1 = eb1 + (size_t)k * HIDN;
  float acc[4][8];
#pragma unroll
  for (int h = 0; h < 4; h++) {
    float b0 = b1[j0 + h], bb = b1[j1 + h];
#pragma unroll
    for (int r = 0; r < 4; r++) { acc[r][h] = b0; acc[r][4 + h] = bb; }
  }

  for (int s = 0; s < NS; s++) {
    __syncthreads();
    if (s + 1 < NS) {
      const float* g = W + (size_t)((s + 1) * BI + wv) * HIDN + lane * 4;
      float* l = &wbuf[(s + 1) & 1][wv][0];
      gload_lds16(g, l);
      gload_lds16(g + 256, l + 256);
    }
    const float(*wb_)[HIDN] = wbuf[s & 1];
    const int i0 = s * BI;
    float4 xv[4];
#pragma unroll
    for (int r = 0; r < 4; r++) xv[r] = *(const float4*)&xe[wv * 4 + r][i0];
#pragma unroll
    for (int ii = 0; ii < BI; ii++) {
      float4 wa = *(const float4*)&wb_[ii][j0];
      float4 wbv = *(const float4*)&wb_[ii][j1];
#pragma unroll
      for (int r = 0; r < 4; r++) {
        const float* xp = (const float*)&xv[r];
        float xs = xp[ii];
        acc[r][0] = fmaf(xs, wa.x, acc[r][0]);
        acc[r][1] = fmaf(xs, wa.y, acc[r][1]);
        acc[r][2] = fmaf(xs, wa.z, acc[r][2]);
        acc[r][3] = fmaf(xs, wa.w, acc[r][3]);
        acc[r][4] = fmaf(xs, wbv.x, acc[r][4]);
        acc[r][5] = fmaf(xs, wbv.y, acc[r][5]);
        acc[r][6] = fmaf(xs, wbv.z, acc[r][6]);
        acc[r][7] = fmaf(xs, wbv.w, acc[r][7]);
      }
    }
  }

  // relu + second layer + wave reduce + gated atomic accumulate
  const float* __restrict__ w2 = ew2 + (size_t)k * HIDN;
  float4 w2a = *(const float4*)(w2 + j0);
  float4 w2b = *(const float4*)(w2 + j1);
  float part[4];
#pragma unroll
  for (int r = 0; r < 4; r++) {
    float p = 0.f;
    p += fmaxf(acc[r][0], 0.f) * w2a.x;
    p += fmaxf(acc[r][1], 0.f) * w2a.y;
    p += fmaxf(acc[r][2], 0.f) * w2a.z;
    p += fmaxf(acc[r][3], 0.f) * w2a.w;
    p += fmaxf(acc[r][4], 0.f) * w2b.x;
    p += fmaxf(acc[r][5], 0.f) * w2b.y;
    p += fmaxf(acc[r][6], 0.f) * w2b.z;
    p += fmaxf(acc[r][7], 0.f) * w2b.w;
    part[r] = p;
  }
#pragma unroll
  for (int off = 1; off < 64; off <<= 1) {
#pragma unroll
    for (int r = 0; r < 4; r++) part[r] += __shfl_xor(part[r], off);
  }
  if (lane == 0) {
    float e2 = eb2[k];
#pragma unroll
    for (int r = 0; r < 4; r++) {
      int rr = wv * 4 + r;
      atomicAdd(&y[rid[rr]], rw[rr] * (part[r] + e2));
    }
  }
}

// ---------------- loss ------------------------------------------------------
__global__ __launch_bounds__(256) void loss_kernel(const int* __restrict__ cnt,
                                                   const float* __restrict__ wlist,
                                                   float* __restrict__ out) {
  __shared__ float simp[KE][KE];
  __shared__ float fimp[KE];
  const int tid = threadIdx.x;
  const int k = tid >> 4, g = tid & 15;
  const int n = cnt[k];
  float s = 0.f;
  for (int j = g; j < n; j += 16) s += wlist[k * Bn + j];
  simp[k][g] = s;
  __syncthreads();
  if (tid < KE) {
    float t = 0.f;
    for (int q = 0; q < KE; q++) t += simp[tid][q];
    fimp[tid] = t;
  }
  __syncthreads();
  if (tid == 0) {
    double mi = 0.0, ml = 0.0;
    for (int q = 0; q < KE; q++) { mi += fimp[q]; ml += (double)cnt[q]; }
    mi /= KE; ml /= KE;
    double vi = 0.0, vl = 0.0;
    for (int q = 0; q < KE; q++) {
      double di = fimp[q] - mi; vi += di * di;
      double dl = (double)cnt[q] - ml; vl += dl * dl;
    }
    vi /= KE; vl /= KE;
    out[Bn] = (float)(vi / (mi * mi + 1e-10) + vl / (ml * ml + 1e-10));
  }
}

extern "C" void kernel_launch(void* const* d_in, const int* in_sizes, int n_in,
                              void* d_out, int out_size, void* d_ws, size_t ws_size,
                              hipStream_t stream) {
  const int* x      = (const int*)d_in[0];
  const int* sql    = (const int*)d_in[1];
  const float* semb = (const float*)d_in[2];
  const float* demb = (const float*)d_in[3];
  const float* gw1  = (const float*)d_in[4];
  const float* gb1  = (const float*)d_in[5];
  const float* gw2  = (const float*)d_in[6];
  const float* gb2  = (const float*)d_in[7];
  const float* ew1  = (const float*)d_in[8];
  const float* eb1  = (const float*)d_in[9];
  const float* ew2  = (const float*)d_in[10];
  const float* eb2  = (const float*)d_in[11];
  float* y = (float*)d_out;

  char* ws = (char*)d_ws;
  int* cnt     = (int*)ws;
  int* list    = (int*)(ws + 1024);
  float* wlist = (float*)(ws + 1024 + sizeof(int) * KE * Bn);

  init_kernel<<<(Bn + 1 + 255) / 256, 256, 0, stream>>>(y, cnt);
  gate_kernel<<<Bn / 16, 256, 0, stream>>>(sql, semb, gw1, gb1, gw2, gb2,
                                           cnt, list, wlist);
  expert_kernel<<<dim3(Bn / 16, KE), 256, 0, stream>>>(x, demb, ew1, eb1, ew2,
                                                       eb2, cnt, list, wlist, y);
  loss_kernel<<<1, 256, 0, stream>>>(cnt, wlist, y);
}

// Round 3
// 139.149 us; speedup vs baseline: 1.7155x; 1.3525x over previous
//
#include <hip/hip_runtime.h>
#include <hip/hip_bf16.h>

#define Bn 4096
#define NF 20
#define NEMB 16
#define HIDN 512
#define KE 16
#define GIN 320
#define BI 8            // K-rows per LDS stage
#define NS (GIN / BI)   // 40 stages
#define CH 256          // cols per half-block

__device__ __forceinline__ void gload_lds16(const float* g, float* l) {
  __builtin_amdgcn_global_load_lds(
      (const __attribute__((address_space(1))) unsigned int*)g,
      (__attribute__((address_space(3))) unsigned int*)l, 16, 0, 0);
}

// ---------------- init ------------------------------------------------------
__global__ __launch_bounds__(256) void init_kernel(float* __restrict__ out,
                                                   int* __restrict__ cnt) {
  int t = blockIdx.x * 256 + threadIdx.x;
  if (t < Bn + 1) out[t] = 0.f;
  if (t < KE) cnt[t] = 0;
}

// ---------------- gate stage 1: partial h-GEMM + partial logits -------------
// block = (row-group of 16, col-half of 256). Writes partial logits to glp.
__global__ __launch_bounds__(256) void gate_kernel(
    const int* __restrict__ sql, const float* __restrict__ semb_w,
    const float* __restrict__ gw1, const float* __restrict__ gb1,
    const float* __restrict__ gw2, float* __restrict__ glp) {
  __shared__ __align__(16) float xe[16][GIN];        // 20 KB
  __shared__ __align__(16) float wbuf[2][BI][CH];    // 16 KB
  const int tid = threadIdx.x;
  const int lane = tid & 63;
  const int wv = tid >> 6;
  const int row0 = blockIdx.x * 16;
  const int ch = blockIdx.y;
  const int cbase = ch * CH;

  for (int p = tid; p < 16 * NF; p += 256) {
    int r = p / NF, f = p % NF;
    int idx = sql[(row0 + r) * NF + f];
    const float4* src = (const float4*)(semb_w + (size_t)idx * NEMB);
    float4* dst = (float4*)&xe[r][f * NEMB];
    dst[0] = src[0]; dst[1] = src[1]; dst[2] = src[2]; dst[3] = src[3];
  }
  const int j0 = lane * 4;
  // prologue: stage 0 (wave wv loads K-rows 2wv, 2wv+1 of the half-panel)
  {
    const float* g = gw1 + (size_t)(2 * wv) * HIDN + cbase + j0;
    gload_lds16(g, &wbuf[0][2 * wv][0]);
    gload_lds16(g + HIDN, &wbuf[0][2 * wv + 1][0]);
  }

  float acc[4][4];
  {
    float4 b = *(const float4*)(gb1 + cbase + j0);
#pragma unroll
    for (int r = 0; r < 4; r++) {
      acc[r][0] = b.x; acc[r][1] = b.y; acc[r][2] = b.z; acc[r][3] = b.w;
    }
  }

  for (int s = 0; s < NS; s++) {
    __syncthreads();
    if (s + 1 < NS) {
      const float* g = gw1 + (size_t)((s + 1) * BI + 2 * wv) * HIDN + cbase + j0;
      float* l = &wbuf[(s + 1) & 1][2 * wv][0];
      gload_lds16(g, l);
      gload_lds16(g + HIDN, l + CH);
    }
    const float(*wb)[CH] = wbuf[s & 1];
    const int i0 = s * BI;
    float xr[4][BI];
#pragma unroll
    for (int r = 0; r < 4; r++) {
      *(float4*)&xr[r][0] = *(const float4*)&xe[wv * 4 + r][i0];
      *(float4*)&xr[r][4] = *(const float4*)&xe[wv * 4 + r][i0 + 4];
    }
#pragma unroll
    for (int ii = 0; ii < BI; ii++) {
      float4 w = *(const float4*)&wb[ii][j0];
#pragma unroll
      for (int r = 0; r < 4; r++) {
        float xs = xr[r][ii];
        acc[r][0] = fmaf(xs, w.x, acc[r][0]);
        acc[r][1] = fmaf(xs, w.y, acc[r][1]);
        acc[r][2] = fmaf(xs, w.z, acc[r][2]);
        acc[r][3] = fmaf(xs, w.w, acc[r][3]);
      }
    }
  }

  // partial logits from my 4 h-columns
  float part[4][KE];
#pragma unroll
  for (int r = 0; r < 4; r++)
#pragma unroll
    for (int q = 0; q < KE; q++) part[r][q] = 0.f;
#pragma unroll
  for (int cc = 0; cc < 4; cc++) {
    const float* g2 = gw2 + (size_t)(cbase + j0 + cc) * KE;
    float4 g0 = *(const float4*)g2;
    float4 g1 = *(const float4*)(g2 + 4);
    float4 g2v = *(const float4*)(g2 + 8);
    float4 g3 = *(const float4*)(g2 + 12);
#pragma unroll
    for (int r = 0; r < 4; r++) {
      float h = fmaxf(acc[r][cc], 0.f);
      part[r][0] += h * g0.x;  part[r][1] += h * g0.y;
      part[r][2] += h * g0.z;  part[r][3] += h * g0.w;
      part[r][4] += h * g1.x;  part[r][5] += h * g1.y;
      part[r][6] += h * g1.z;  part[r][7] += h * g1.w;
      part[r][8] += h * g2v.x; part[r][9] += h * g2v.y;
      part[r][10] += h * g2v.z; part[r][11] += h * g2v.w;
      part[r][12] += h * g3.x; part[r][13] += h * g3.y;
      part[r][14] += h * g3.z; part[r][15] += h * g3.w;
    }
  }
#pragma unroll
  for (int off = 1; off < 64; off <<= 1)
#pragma unroll
    for (int r = 0; r < 4; r++)
#pragma unroll
      for (int q = 0; q < KE; q++) part[r][q] += __shfl_xor(part[r][q], off);
  if (lane == 0) {
#pragma unroll
    for (int r = 0; r < 4; r++) {
      float* dst = glp + ((size_t)ch * Bn + row0 + wv * 4 + r) * KE;
      *(float4*)(dst + 0) = make_float4(part[r][0], part[r][1], part[r][2], part[r][3]);
      *(float4*)(dst + 4) = make_float4(part[r][4], part[r][5], part[r][6], part[r][7]);
      *(float4*)(dst + 8) = make_float4(part[r][8], part[r][9], part[r][10], part[r][11]);
      *(float4*)(dst + 12) = make_float4(part[r][12], part[r][13], part[r][14], part[r][15]);
    }
  }
}

// ---------------- gate stage 2: softmax + top-2 + bucket --------------------
__global__ __launch_bounds__(256) void gate2_kernel(
    const float* __restrict__ glp, const float* __restrict__ gb2,
    int* __restrict__ cnt, int* __restrict__ list, float* __restrict__ wlist) {
  __shared__ int lcnt[KE];
  __shared__ int gbase[KE];
  const int tid = threadIdx.x;
  const int row = blockIdx.x * 256 + tid;
  if (tid < KE) lcnt[tid] = 0;
  __syncthreads();
  float lg[KE];
  {
    const float4* a = (const float4*)(glp + (size_t)row * KE);
    const float4* b = (const float4*)(glp + ((size_t)Bn + row) * KE);
    const float4* c = (const float4*)gb2;
#pragma unroll
    for (int u = 0; u < 4; u++) {
      float4 av = a[u], bv = b[u], cv = c[u];
      lg[u * 4 + 0] = av.x + bv.x + cv.x;
      lg[u * 4 + 1] = av.y + bv.y + cv.y;
      lg[u * 4 + 2] = av.z + bv.z + cv.z;
      lg[u * 4 + 3] = av.w + bv.w + cv.w;
    }
  }
  float m = lg[0];
#pragma unroll
  for (int q = 1; q < KE; q++) m = fmaxf(m, lg[q]);
  float e[KE];
#pragma unroll
  for (int q = 0; q < KE; q++) e[q] = expf(lg[q] - m);
  int i1 = 0; float v1 = e[0];
#pragma unroll
  for (int q = 1; q < KE; q++) if (e[q] > v1) { v1 = e[q]; i1 = q; }
  int i2 = (i1 == 0) ? 1 : 0; float v2 = e[i2];
#pragma unroll
  for (int q = 0; q < KE; q++)
    if (q != i1 && e[q] > v2) { v2 = e[q]; i2 = q; }
  int o1 = atomicAdd(&lcnt[i1], 1);
  int o2 = atomicAdd(&lcnt[i2], 1);
  __syncthreads();
  if (tid < KE) gbase[tid] = atomicAdd(&cnt[tid], lcnt[tid]);
  __syncthreads();
  float den = v1 + v2;
  int s1 = gbase[i1] + o1;
  list[i1 * Bn + s1] = row; wlist[i1 * Bn + s1] = v1 / den;
  int s2 = gbase[i2] + o2;
  list[i2 * Bn + s2] = row; wlist[i2 * Bn + s2] = v2 / den;
}

// ---------------- scheduler: compact (expert, chunk) work list --------------
__global__ void sched_kernel(const int* __restrict__ cnt,
                             int* __restrict__ nitems, int* __restrict__ items) {
  __shared__ int pref[KE + 1];
  const int tid = threadIdx.x;
  if (tid == 0) {
    int s = 0;
    for (int k = 0; k < KE; k++) { pref[k] = s; s += (cnt[k] + 15) >> 4; }
    pref[KE] = s;
    *nitems = s;
  }
  __syncthreads();
  if (tid < KE) {
    int nchunk = (cnt[tid] + 15) >> 4;
    for (int c = 0; c < nchunk; c++) items[pref[tid] + c] = tid | (c << 8);
  }
}

// ---------------- experts: work-list driven, col-half blocks ----------------
__global__ __launch_bounds__(256) void expert_kernel(
    const int* __restrict__ x, const float* __restrict__ demb_w,
    const float* __restrict__ ew1, const float* __restrict__ eb1,
    const float* __restrict__ ew2, const float* __restrict__ eb2,
    const int* __restrict__ cnt, const int* __restrict__ nitems_p,
    const int* __restrict__ items, const int* __restrict__ list,
    const float* __restrict__ wlist, float* __restrict__ y) {
  __shared__ __align__(16) float xe[16][GIN];
  __shared__ __align__(16) float wbuf[2][BI][CH];
  __shared__ int rid[16];
  __shared__ float rw[16];
  const int tid = threadIdx.x;
  const int lane = tid & 63;
  const int wv = tid >> 6;
  const int ch = blockIdx.y;
  const int cbase = ch * CH;
  const int j0 = lane * 4;
  const int nit = *nitems_p;

  for (int it = blockIdx.x; it < nit; it += gridDim.x) {
    __syncthreads();  // previous item fully done before reusing LDS
    const int pk = items[it];
    const int k = pk & 255;
    const int base = (pk >> 8) << 4;
    const int n = cnt[k];
    if (tid < 16) {
      if (base + tid < n) {
        rid[tid] = list[k * Bn + base + tid];
        rw[tid] = wlist[k * Bn + base + tid];
      } else {
        rid[tid] = 0; rw[tid] = 0.f;
      }
    }
    __syncthreads();
    for (int p = tid; p < 16 * NF; p += 256) {
      int r = p / NF, f = p % NF;
      int idx = x[rid[r] * NF + f];
      const float4* src = (const float4*)(demb_w + (size_t)idx * NEMB);
      float4* dst = (float4*)&xe[r][f * NEMB];
      dst[0] = src[0]; dst[1] = src[1]; dst[2] = src[2]; dst[3] = src[3];
    }
    const float* __restrict__ W = ew1 + (size_t)k * GIN * HIDN;
    {
      const float* g = W + (size_t)(2 * wv) * HIDN + cbase + j0;
      gload_lds16(g, &wbuf[0][2 * wv][0]);
      gload_lds16(g + HIDN, &wbuf[0][2 * wv + 1][0]);
    }
    float acc[4][4];
    {
      float4 b = *(const float4*)(eb1 + (size_t)k * HIDN + cbase + j0);
#pragma unroll
      for (int r = 0; r < 4; r++) {
        acc[r][0] = b.x; acc[r][1] = b.y; acc[r][2] = b.z; acc[r][3] = b.w;
      }
    }
    for (int s = 0; s < NS; s++) {
      __syncthreads();
      if (s + 1 < NS) {
        const float* g = W + (size_t)((s + 1) * BI + 2 * wv) * HIDN + cbase + j0;
        float* l = &wbuf[(s + 1) & 1][2 * wv][0];
        gload_lds16(g, l);
        gload_lds16(g + HIDN, l + CH);
      }
      const float(*wb)[CH] = wbuf[s & 1];
      const int i0 = s * BI;
      float xr[4][BI];
#pragma unroll
      for (int r = 0; r < 4; r++) {
        *(float4*)&xr[r][0] = *(const float4*)&xe[wv * 4 + r][i0];
        *(float4*)&xr[r][4] = *(const float4*)&xe[wv * 4 + r][i0 + 4];
      }
#pragma unroll
      for (int ii = 0; ii < BI; ii++) {
        float4 w = *(const float4*)&wb[ii][j0];
#pragma unroll
        for (int r = 0; r < 4; r++) {
          float xs = xr[r][ii];
          acc[r][0] = fmaf(xs, w.x, acc[r][0]);
          acc[r][1] = fmaf(xs, w.y, acc[r][1]);
          acc[r][2] = fmaf(xs, w.z, acc[r][2]);
          acc[r][3] = fmaf(xs, w.w, acc[r][3]);
        }
      }
    }
    // second layer on my col-half + wave reduce + gated atomic accumulate
    float4 w2v = *(const float4*)(ew2 + (size_t)k * HIDN + cbase + j0);
    float part[4];
#pragma unroll
    for (int r = 0; r < 4; r++) {
      float p = 0.f;
      p += fmaxf(acc[r][0], 0.f) * w2v.x;
      p += fmaxf(acc[r][1], 0.f) * w2v.y;
      p += fmaxf(acc[r][2], 0.f) * w2v.z;
      p += fmaxf(acc[r][3], 0.f) * w2v.w;
      part[r] = p;
    }
#pragma unroll
    for (int off = 1; off < 64; off <<= 1)
#pragma unroll
      for (int r = 0; r < 4; r++) part[r] += __shfl_xor(part[r], off);
    if (lane == 0) {
      float e2 = (ch == 0) ? eb2[k] : 0.f;
#pragma unroll
      for (int r = 0; r < 4; r++) {
        int rr = wv * 4 + r;
        atomicAdd(&y[rid[rr]], rw[rr] * (part[r] + e2));
      }
    }
  }
}

// ---------------- loss ------------------------------------------------------
__global__ __launch_bounds__(256) void loss_kernel(const int* __restrict__ cnt,
                                                   const float* __restrict__ wlist,
                                                   float* __restrict__ out) {
  __shared__ float simp[KE][KE];
  __shared__ float fimp[KE];
  const int tid = threadIdx.x;
  const int k = tid >> 4, g = tid & 15;
  const int n = cnt[k];
  float s = 0.f;
  for (int j = g; j < n; j += 16) s += wlist[k * Bn + j];
  simp[k][g] = s;
  __syncthreads();
  if (tid < KE) {
    float t = 0.f;
    for (int q = 0; q < KE; q++) t += simp[tid][q];
    fimp[tid] = t;
  }
  __syncthreads();
  if (tid == 0) {
    double mi = 0.0, ml = 0.0;
    for (int q = 0; q < KE; q++) { mi += fimp[q]; ml += (double)cnt[q]; }
    mi /= KE; ml /= KE;
    double vi = 0.0, vl = 0.0;
    for (int q = 0; q < KE; q++) {
      double di = fimp[q] - mi; vi += di * di;
      double dl = (double)cnt[q] - ml; vl += dl * dl;
    }
    vi /= KE; vl /= KE;
    out[Bn] = (float)(vi / (mi * mi + 1e-10) + vl / (ml * ml + 1e-10));
  }
}

extern "C" void kernel_launch(void* const* d_in, const int* in_sizes, int n_in,
                              void* d_out, int out_size, void* d_ws, size_t ws_size,
                              hipStream_t stream) {
  const int* x      = (const int*)d_in[0];
  const int* sql    = (const int*)d_in[1];
  const float* semb = (const float*)d_in[2];
  const float* demb = (const float*)d_in[3];
  const float* gw1  = (const float*)d_in[4];
  const float* gb1  = (const float*)d_in[5];
  const float* gw2  = (const float*)d_in[6];
  const float* gb2  = (const float*)d_in[7];
  const float* ew1  = (const float*)d_in[8];
  const float* eb1  = (const float*)d_in[9];
  const float* ew2  = (const float*)d_in[10];
  const float* eb2  = (const float*)d_in[11];
  float* y = (float*)d_out;

  char* ws = (char*)d_ws;
  int* cnt     = (int*)ws;                      // 16 ints
  int* nitems  = (int*)(ws + 64);               // 1 int
  int* items   = (int*)(ws + 256);              // <=1024 ints
  int* list    = (int*)(ws + 8192);             // KE*Bn ints (256 KB)
  float* wlist = (float*)(ws + 8192 + 262144);  // KE*Bn floats (256 KB)
  float* glp   = (float*)(ws + 8192 + 524288);  // 2*Bn*KE floats (512 KB)

  init_kernel<<<17, 256, 0, stream>>>(y, cnt);
  gate_kernel<<<dim3(Bn / 16, 2), 256, 0, stream>>>(sql, semb, gw1, gb1, gw2, glp);
  gate2_kernel<<<Bn / 256, 256, 0, stream>>>(glp, gb2, cnt, list, wlist);
  sched_kernel<<<1, 64, 0, stream>>>(cnt, nitems, items);
  expert_kernel<<<dim3(512, 2), 256, 0, stream>>>(x, demb, ew1, eb1, ew2, eb2,
                                                  cnt, nitems, items, list, wlist, y);
  loss_kernel<<<1, 256, 0, stream>>>(cnt, wlist, y);
}

// Round 4
// 107.291 us; speedup vs baseline: 2.2249x; 1.2969x over previous
//
#include <hip/hip_runtime.h>

#define Bn 4096
#define NF 20
#define NEMB 16
#define HIDN 512
#define KE 16
#define GIN 320
#define NKS 10   // K-steps of 32

typedef __attribute__((ext_vector_type(8))) short short8;
typedef __attribute__((ext_vector_type(4))) float f32x4;

__device__ __forceinline__ unsigned short f2bf(float f) {
  unsigned int u = __builtin_bit_cast(unsigned int, f);
  u += 0x7fff + ((u >> 16) & 1);
  return (unsigned short)(u >> 16);
}
__device__ __forceinline__ float bf2f(unsigned short h) {
  unsigned int u = ((unsigned int)h) << 16;
  return __builtin_bit_cast(float, u);
}

// ---------------- prep: gathers, bf16 conversion, fragment-ordered weights --
// sections: XE(81920) SE(81920) GW(40960) EW(327680) zero(4113)
__global__ __launch_bounds__(256) void prep_kernel(
    const int* __restrict__ x, const int* __restrict__ sql,
    const float* __restrict__ demb, const float* __restrict__ semb,
    const float* __restrict__ gw1, const float* __restrict__ ew1,
    unsigned short* __restrict__ XE, unsigned short* __restrict__ SH,
    unsigned short* __restrict__ SL, unsigned short* __restrict__ GWF,
    unsigned short* __restrict__ EWF, float* __restrict__ y,
    int* __restrict__ cnt) {
  long long t = (long long)blockIdx.x * 256 + threadIdx.x;
  if (t < 81920) {
    int row = (int)(t / NF), f = (int)(t % NF);
    int idx = x[row * NF + f];
    const float* s = demb + (size_t)idx * NEMB;
    short8 o0, o1;
#pragma unroll
    for (int i = 0; i < 8; i++) {
      o0[i] = (short)f2bf(s[i]);
      o1[i] = (short)f2bf(s[8 + i]);
    }
    size_t o = (size_t)row * GIN + f * NEMB;
    *(short8*)(XE + o) = o0;
    *(short8*)(XE + o + 8) = o1;
    return;
  }
  t -= 81920;
  if (t < 81920) {
    int row = (int)(t / NF), f = (int)(t % NF);
    int idx = sql[row * NF + f];
    const float* s = semb + (size_t)idx * NEMB;
    short8 h0, h1, l0, l1;
#pragma unroll
    for (int i = 0; i < 8; i++) {
      float v = s[i];
      unsigned short hb = f2bf(v);
      h0[i] = (short)hb; l0[i] = (short)f2bf(v - bf2f(hb));
      v = s[8 + i];
      hb = f2bf(v);
      h1[i] = (short)hb; l1[i] = (short)f2bf(v - bf2f(hb));
    }
    size_t o = (size_t)row * GIN + f * NEMB;
    *(short8*)(SH + o) = h0; *(short8*)(SH + o + 8) = h1;
    *(short8*)(SL + o) = l0; *(short8*)(SL + o + 8) = l1;
    return;
  }
  t -= 81920;
  if (t < 40960) {
    int s = (int)(t / 20480), r = (int)(t % 20480);
    int ks = r / 2048, r2 = r % 2048, nt = r2 / 64, l = r2 % 64;
    int k0 = ks * 32 + (l >> 4) * 8, n = nt * 16 + (l & 15);
    short8 o;
#pragma unroll
    for (int j = 0; j < 8; j++) {
      float w = gw1[(size_t)(k0 + j) * HIDN + n];
      unsigned short hb = f2bf(w);
      o[j] = (s == 0) ? (short)hb : (short)f2bf(w - bf2f(hb));
    }
    *(short8*)(GWF + ((((size_t)s * NKS + ks) * 32 + nt) * 64 + l) * 8) = o;
    return;
  }
  t -= 40960;
  if (t < 327680) {
    int e = (int)(t / 20480), r = (int)(t % 20480);
    int ks = r / 2048, r2 = r % 2048, nt = r2 / 64, l = r2 % 64;
    int k0 = ks * 32 + (l >> 4) * 8, n = nt * 16 + (l & 15);
    const float* W = ew1 + (size_t)e * GIN * HIDN;
    short8 o;
#pragma unroll
    for (int j = 0; j < 8; j++) o[j] = (short)f2bf(W[(size_t)(k0 + j) * HIDN + n]);
    *(short8*)(EWF + ((((size_t)e * NKS + ks) * 32 + nt) * 64 + l) * 8) = o;
    return;
  }
  t -= 327680;
  if (t < Bn + 1) y[t] = 0.f;
  else if (t < Bn + 1 + KE) cnt[t - (Bn + 1)] = 0;
}

// ---------------- gate: split-bf16 MFMA GEMM + partial logits ---------------
// grid (256 rowgroups, 4 col-blocks of 128)
__global__ __launch_bounds__(256) void gate_kernel(
    const unsigned short* __restrict__ SH, const unsigned short* __restrict__ SL,
    const unsigned short* __restrict__ GWF, const float* __restrict__ gb1,
    const float* __restrict__ gw2, float* __restrict__ glp) {
  __shared__ __align__(16) unsigned short bsh[2][16][512];  // 32 KB
  __shared__ float hs[16][128];                             // 8 KB
  const int tid = threadIdx.x, lane = tid & 63, wv = tid >> 6;
  const int row0 = blockIdx.x * 16, nb = blockIdx.y, nbase = nb * 128;
  const int rrow = row0 + (lane & 15);
  const int ko = (lane >> 4) * 8;

  short8 ah[NKS], al[NKS];
#pragma unroll
  for (int ks = 0; ks < NKS; ks++) {
    size_t o = (size_t)rrow * GIN + ks * 32 + ko;
    ah[ks] = *(const short8*)(SH + o);
    al[ks] = *(const short8*)(SL + o);
  }
  f32x4 acc[2] = {};

#define GSTAGE(buf, ks)                                                         \
  {                                                                             \
    _Pragma("unroll") for (int i = 0; i < 4; i++) {                             \
      int c = wv * 4 + i;                                                       \
      const unsigned short* g = GWF +                                           \
          ((((size_t)(c >> 3) * NKS + (ks)) * 32) + nb * 8 + (c & 7)) * 512 +   \
          lane * 8;                                                             \
      __builtin_amdgcn_global_load_lds(                                         \
          (const __attribute__((address_space(1))) unsigned int*)g,             \
          (__attribute__((address_space(3))) unsigned int*)&bsh[buf][c][lane * 8], \
          16, 0, 0);                                                            \
    }                                                                           \
  }

  GSTAGE(0, 0)
#pragma unroll
  for (int ks = 0; ks < NKS; ks++) {
    __syncthreads();
    if (ks + 1 < NKS) GSTAGE((ks + 1) & 1, ks + 1)
#pragma unroll
    for (int nt = 0; nt < 2; nt++) {
      int ntl = wv * 2 + nt;
      short8 bh = *(const short8*)&bsh[ks & 1][ntl][lane * 8];
      short8 bl = *(const short8*)&bsh[ks & 1][8 + ntl][lane * 8];
      acc[nt] = __builtin_amdgcn_mfma_f32_16x16x32_bf16(ah[ks], bh, acc[nt], 0, 0, 0);
      acc[nt] = __builtin_amdgcn_mfma_f32_16x16x32_bf16(al[ks], bh, acc[nt], 0, 0, 0);
      acc[nt] = __builtin_amdgcn_mfma_f32_16x16x32_bf16(ah[ks], bl, acc[nt], 0, 0, 0);
    }
  }

  // bias + relu -> hs
#pragma unroll
  for (int nt = 0; nt < 2; nt++) {
    int cl = wv * 32 + nt * 16 + (lane & 15);
    float b = gb1[nbase + cl];
#pragma unroll
    for (int j = 0; j < 4; j++)
      hs[(lane >> 4) * 4 + j][cl] = fmaxf(acc[nt][j] + b, 0.f);
  }
  __syncthreads();
  {
    int row = tid >> 4, q = tid & 15;
    float s = 0.f;
    for (int c = 0; c < 128; c++)
      s = fmaf(hs[row][c], gw2[(size_t)(nbase + c) * KE + q], s);
    glp[((size_t)nb * Bn + row0 + row) * KE + q] = s;
  }
}

// ---------------- gate2: sum partials, softmax, top-2, bucket ---------------
__global__ __launch_bounds__(256) void gate2_kernel(
    const float* __restrict__ glp, const float* __restrict__ gb2,
    int* __restrict__ cnt, int* __restrict__ list, float* __restrict__ wlist) {
  __shared__ int lcnt[KE];
  __shared__ int gbase[KE];
  const int tid = threadIdx.x;
  const int row = blockIdx.x * 256 + tid;
  if (tid < KE) lcnt[tid] = 0;
  __syncthreads();
  float lg[KE];
  {
    const float4* c = (const float4*)gb2;
#pragma unroll
    for (int u = 0; u < 4; u++) {
      float4 s = c[u];
      lg[u * 4 + 0] = s.x; lg[u * 4 + 1] = s.y;
      lg[u * 4 + 2] = s.z; lg[u * 4 + 3] = s.w;
    }
#pragma unroll
    for (int sl = 0; sl < 4; sl++) {
      const float4* a = (const float4*)(glp + ((size_t)sl * Bn + row) * KE);
#pragma unroll
      for (int u = 0; u < 4; u++) {
        float4 v = a[u];
        lg[u * 4 + 0] += v.x; lg[u * 4 + 1] += v.y;
        lg[u * 4 + 2] += v.z; lg[u * 4 + 3] += v.w;
      }
    }
  }
  float m = lg[0];
#pragma unroll
  for (int q = 1; q < KE; q++) m = fmaxf(m, lg[q]);
  float e[KE];
#pragma unroll
  for (int q = 0; q < KE; q++) e[q] = expf(lg[q] - m);
  int i1 = 0; float v1 = e[0];
#pragma unroll
  for (int q = 1; q < KE; q++) if (e[q] > v1) { v1 = e[q]; i1 = q; }
  int i2 = (i1 == 0) ? 1 : 0; float v2 = e[i2];
#pragma unroll
  for (int q = 0; q < KE; q++)
    if (q != i1 && e[q] > v2) { v2 = e[q]; i2 = q; }
  int o1 = atomicAdd(&lcnt[i1], 1);
  int o2 = atomicAdd(&lcnt[i2], 1);
  __syncthreads();
  if (tid < KE) gbase[tid] = atomicAdd(&cnt[tid], lcnt[tid]);
  __syncthreads();
  float den = v1 + v2;
  int s1 = gbase[i1] + o1;
  list[i1 * Bn + s1] = row; wlist[i1 * Bn + s1] = v1 / den;
  int s2 = gbase[i2] + o2;
  list[i2 * Bn + s2] = row; wlist[i2 * Bn + s2] = v2 / den;
}

// ---------------- experts: bf16 MFMA, 32-row chunks, in-block scheduling ----
// grid (272, 2 col-halves of 256)
__global__ __launch_bounds__(256) void expert_kernel(
    const unsigned short* __restrict__ XE, const unsigned short* __restrict__ EWF,
    const float* __restrict__ eb1, const float* __restrict__ ew2,
    const float* __restrict__ eb2, const int* __restrict__ cnt,
    const int* __restrict__ list, const float* __restrict__ wlist,
    float* __restrict__ y) {
  __shared__ __align__(16) unsigned short bsh[2][16][512];  // 32 KB
  __shared__ int rid[32];
  __shared__ float rw[32];
  const int tid = threadIdx.x, lane = tid & 63, wv = tid >> 6;
  const int item = blockIdx.x, ch = blockIdx.y;
  int k = -1, base = 0, pref = 0;
#pragma unroll
  for (int q = 0; q < KE; q++) {
    int nc = (cnt[q] + 31) >> 5;
    if (item >= pref && item < pref + nc) { k = q; base = (item - pref) * 32; }
    pref += nc;
  }
  if (k < 0) return;
  const int n = cnt[k];
  if (tid < 32) {
    int p = base + tid;
    rid[tid] = (p < n) ? list[k * Bn + p] : 0;
    rw[tid] = (p < n) ? wlist[k * Bn + p] : 0.f;
  }
  __syncthreads();
  const int ko = (lane >> 4) * 8;
  short8 a[2][NKS];
#pragma unroll
  for (int mt = 0; mt < 2; mt++) {
    int rr = rid[mt * 16 + (lane & 15)];
#pragma unroll
    for (int ks = 0; ks < NKS; ks++)
      a[mt][ks] = *(const short8*)(XE + (size_t)rr * GIN + ks * 32 + ko);
  }
  f32x4 acc[2][4] = {};

#define ESTAGE(buf, ks)                                                         \
  {                                                                             \
    _Pragma("unroll") for (int i = 0; i < 4; i++) {                             \
      int c = wv * 4 + i;                                                       \
      const unsigned short* g = EWF +                                           \
          (((size_t)k * NKS + (ks)) * 32 + ch * 16 + c) * 512 + lane * 8;       \
      __builtin_amdgcn_global_load_lds(                                         \
          (const __attribute__((address_space(1))) unsigned int*)g,             \
          (__attribute__((address_space(3))) unsigned int*)&bsh[buf][c][lane * 8], \
          16, 0, 0);                                                            \
    }                                                                           \
  }

  ESTAGE(0, 0)
#pragma unroll
  for (int ks = 0; ks < NKS; ks++) {
    __syncthreads();
    if (ks + 1 < NKS) ESTAGE((ks + 1) & 1, ks + 1)
#pragma unroll
    for (int nt = 0; nt < 4; nt++) {
      int ntl = wv * 4 + nt;
      short8 b = *(const short8*)&bsh[ks & 1][ntl][lane * 8];
#pragma unroll
      for (int mt = 0; mt < 2; mt++)
        acc[mt][nt] = __builtin_amdgcn_mfma_f32_16x16x32_bf16(a[mt][ks], b, acc[mt][nt], 0, 0, 0);
    }
  }
  // epilogue: bias + relu + dot w2 + reduce over 16 lanes + gated atomic
  float part[2][4];
#pragma unroll
  for (int mt = 0; mt < 2; mt++)
#pragma unroll
    for (int j = 0; j < 4; j++) part[mt][j] = 0.f;
#pragma unroll
  for (int nt = 0; nt < 4; nt++) {
    int colg = ch * 256 + (wv * 4 + nt) * 16 + (lane & 15);
    float b1 = eb1[(size_t)k * HIDN + colg];
    float w2 = ew2[(size_t)k * HIDN + colg];
#pragma unroll
    for (int mt = 0; mt < 2; mt++)
#pragma unroll
      for (int j = 0; j < 4; j++)
        part[mt][j] += fmaxf(acc[mt][nt][j] + b1, 0.f) * w2;
  }
#pragma unroll
  for (int off = 8; off >= 1; off >>= 1)
#pragma unroll
    for (int mt = 0; mt < 2; mt++)
#pragma unroll
      for (int j = 0; j < 4; j++)
        part[mt][j] += __shfl_xor(part[mt][j], off);
  if ((lane & 15) == 0) {
    float e2 = (ch == 0) ? eb2[k] : 0.f;
#pragma unroll
    for (int mt = 0; mt < 2; mt++)
#pragma unroll
      for (int j = 0; j < 4; j++) {
        int rl = mt * 16 + (lane >> 4) * 4 + j;
        atomicAdd(&y[rid[rl]], rw[rl] * (part[mt][j] + e2));
      }
  }
}

// ---------------- loss ------------------------------------------------------
__global__ __launch_bounds__(256) void loss_kernel(const int* __restrict__ cnt,
                                                   const float* __restrict__ wlist,
                                                   float* __restrict__ out) {
  __shared__ float simp[KE][KE];
  __shared__ float fimp[KE];
  const int tid = threadIdx.x;
  const int k = tid >> 4, g = tid & 15;
  const int n = cnt[k];
  float s = 0.f;
  for (int j = g; j < n; j += 16) s += wlist[k * Bn + j];
  simp[k][g] = s;
  __syncthreads();
  if (tid < KE) {
    float t = 0.f;
    for (int q = 0; q < KE; q++) t += simp[tid][q];
    fimp[tid] = t;
  }
  __syncthreads();
  if (tid == 0) {
    double mi = 0.0, ml = 0.0;
    for (int q = 0; q < KE; q++) { mi += fimp[q]; ml += (double)cnt[q]; }
    mi /= KE; ml /= KE;
    double vi = 0.0, vl = 0.0;
    for (int q = 0; q < KE; q++) {
      double di = fimp[q] - mi; vi += di * di;
      double dl = (double)cnt[q] - ml; vl += dl * dl;
    }
    vi /= KE; vl /= KE;
    out[Bn] = (float)(vi / (mi * mi + 1e-10) + vl / (ml * ml + 1e-10));
  }
}

extern "C" void kernel_launch(void* const* d_in, const int* in_sizes, int n_in,
                              void* d_out, int out_size, void* d_ws, size_t ws_size,
                              hipStream_t stream) {
  const int* x      = (const int*)d_in[0];
  const int* sql    = (const int*)d_in[1];
  const float* semb = (const float*)d_in[2];
  const float* demb = (const float*)d_in[3];
  const float* gw1  = (const float*)d_in[4];
  const float* gb1  = (const float*)d_in[5];
  const float* gw2  = (const float*)d_in[6];
  const float* gb2  = (const float*)d_in[7];
  const float* ew1  = (const float*)d_in[8];
  const float* eb1  = (const float*)d_in[9];
  const float* ew2  = (const float*)d_in[10];
  const float* eb2  = (const float*)d_in[11];
  float* y = (float*)d_out;

  char* ws = (char*)d_ws;
  int* cnt            = (int*)(ws);               // 64 B
  int* list           = (int*)(ws + 4096);        // 256 KB
  float* wlist        = (float*)(ws + 266240);    // 256 KB
  float* glp          = (float*)(ws + 528384);    // 1 MB (4 slices)
  unsigned short* XE  = (unsigned short*)(ws + 1576960);   // 2.62 MB
  unsigned short* SH  = (unsigned short*)(ws + 4198400);   // 2.62 MB
  unsigned short* SL  = (unsigned short*)(ws + 6819840);   // 2.62 MB
  unsigned short* GWF = (unsigned short*)(ws + 9441280);   // 655 KB
  unsigned short* EWF = (unsigned short*)(ws + 10096640);  // 5.24 MB -> 15.3 MB total

  prep_kernel<<<2097, 256, 0, stream>>>(x, sql, demb, semb, gw1, ew1,
                                        XE, SH, SL, GWF, EWF, y, cnt);
  gate_kernel<<<dim3(Bn / 16, 4), 256, 0, stream>>>(SH, SL, GWF, gb1, gw2, glp);
  gate2_kernel<<<Bn / 256, 256, 0, stream>>>(glp, gb2, cnt, list, wlist);
  expert_kernel<<<dim3(272, 2), 256, 0, stream>>>(XE, EWF, eb1, ew2, eb2,
                                                  cnt, list, wlist, y);
  loss_kernel<<<1, 256, 0, stream>>>(cnt, wlist, y);
}